// Round 17
// baseline (29.498 us; speedup 1.0000x reference)
//
#include <hip/hip_runtime.h>
#include <hip/hip_bf16.h>

// B=16, Ci=16, Co=16, H=W=24, hidden=64.
// kt:    K[dy47][dxi][o][i] bf16; dy47 = dy+23 in [0,47), dxi = dx+24 in [0,49).
//        dxi stride = 256 shorts.
// vpad2: bf16 [y'=40][x'=40][b=16][i=16], y'=h+8, x'=w+8, zero halo.
// r17: 2-kernel pipeline (combine + part eliminated).
//   conv_direct: grid (wt6, h24) = 144 blocks x 512 thr. Block owns output row
//   h, cols w0..w0+3. t = H2 in [0,24) == full dy sum, split 8 ways over waves
//   (3 t-iters each, acc persists). Sliding-A loop as r12. 8-wave LDS reduce,
//   scale + bias, direct float4 out write. No atomics (r13), no coop sync (r14).

typedef __attribute__((ext_vector_type(8))) short bf16x8;
typedef __attribute__((ext_vector_type(4))) float f32x4;

#define KT_ELEMS (47*49*256)          // 589,568 bf16
#define VPAD2_ELEMS (40*40*256)       // 409,600 bf16
#define NROWS (47*49)                 // 2303 MLP rows
#define NPOS 576                      // 24*24 output positions
#define PREP_BUILD_BLOCKS 288         // ceil(2303/8)
#define PREP_PAD_BLOCKS (VPAD2_ELEMS/256)   // 1600

// ---------------- Kernel 1: prep = build K table + pad v (fused grid) -------
__launch_bounds__(256)
__global__ void prep(const float* __restrict__ v,
                     const float* __restrict__ w1, const float* __restrict__ b1,
                     const float* __restrict__ w2, const float* __restrict__ b2,
                     __hip_bfloat16* __restrict__ kt, __hip_bfloat16* __restrict__ vpad)
{
    const int tid = threadIdx.x;

    if (blockIdx.x >= PREP_BUILD_BLOCKS) {
        // ---- pad part: vpad2[y][x][b][i] ----
        int idx = (blockIdx.x - PREP_BUILD_BLOCKS)*256 + tid;
        if (idx >= VPAD2_ELEMS) return;
        int i = idx & 15;
        int b = (idx >> 4) & 15;
        int s = idx >> 8;             // y*40 + x
        int x = s % 40;
        int y = s / 40;
        int h = y - 8, w = x - 8;
        float val = 0.0f;
        if (h >= 0 && h < 24 && w >= 0 && w < 24)
            val = v[((b*16 + i)*24 + h)*24 + w];
        vpad[idx] = __float2bfloat16(val);
        return;
    }

    // ---- build part: 8 rows of the [2303 x 256] K GEMM per block ----
    __shared__ float ty_s[47];
    __shared__ float tx_s[49];
    __shared__ float hid_s[8][64];
    const int r0 = blockIdx.x * 8;

    if (tid < 47)               ty_s[tid]      = tanhf((float)(tid - 23) * (1.0f/6.0f));
    if (tid >= 64 && tid < 113) tx_s[tid - 64] = tanhf((float)(tid - 64 - 24) * (1.0f/6.0f));
    __syncthreads();

    #pragma unroll
    for (int k = 0; k < 2; ++k) {
        int idx = k*256 + tid;
        int rr  = idx >> 6;
        int j   = idx & 63;
        int r   = r0 + rr;
        if (r >= NROWS) r = NROWS - 1;
        int dy47 = r / 49;
        int dxi  = r % 49;
        float x = ty_s[dy47]*w1[2*j] + tx_s[dxi]*w1[2*j+1] + b1[j];
        hid_s[rr][j] = 0.5f*x*(1.0f + erff(x*0.70710678118f));
    }
    __syncthreads();

    const int c = tid;
    float acc[8];
    const float bb = b2[c];
    #pragma unroll
    for (int r = 0; r < 8; ++r) acc[r] = bb;

    const float4* w2v = (const float4*)w2;
    #pragma unroll
    for (int jv = 0; jv < 16; ++jv) {
        float4 wv = w2v[c*16 + jv];
        #pragma unroll
        for (int e = 0; e < 4; ++e) {
            float we = ((const float*)&wv)[e];
            int j = jv*4 + e;
            #pragma unroll
            for (int r = 0; r < 8; ++r)
                acc[r] += hid_s[r][j] * we;
        }
    }

    #pragma unroll
    for (int rr = 0; rr < 8; ++rr) {
        int r = r0 + rr;
        if (r >= NROWS) break;
        kt[r*256 + c] = __float2bfloat16(acc[rr]);
    }
}

// ---------------- Kernel 2: direct-output MFMA conv ----------------
// Block = (wt, h): output row h, cols w0..w0+3. Wave wv: t = wv + 8k, k<3,
// t == H2; dy47 = t - h + 23 in [0,47). A(ww,dxp): dxi = 24-w0-ww+2dxp+d
// (range [1,47] < 49). B: y' = t+8 in [8,32), x' = 8+2dxp+d in [8,32).
__launch_bounds__(512)
__global__ void conv_direct(const __hip_bfloat16* __restrict__ kt_,
                            const __hip_bfloat16* __restrict__ vpad_,
                            const float* __restrict__ bias,
                            float* __restrict__ out)
{
    __shared__ f32x4 red[8][4][64];   // 32 KB; first 4 KB reused as lds2
    const short* kt = (const short*)kt_;
    const short* vp = (const short*)vpad_;

    const int wt = blockIdx.x;        // 0..5  -> w0 = wt*4
    const int h  = blockIdx.y;        // 0..23
    const int w0 = wt * 4;

    const int tid  = threadIdx.x;
    const int lane = tid & 63;
    const int wv   = tid >> 6;        // 0..7
    const int n    = lane & 15;       // A: o row; B: b col
    const int g    = lane >> 4;       // k-group
    const int d    = g >> 1;          // dx sub-offset within pair
    const int ih   = (g & 1) * 8;     // i-half

    f32x4 acc[4];
    #pragma unroll
    for (int ww = 0; ww < 4; ++ww) acc[ww] = (f32x4){0.f,0.f,0.f,0.f};

    #pragma unroll
    for (int k = 0; k < 3; ++k) {
        const int t = wv + k*8;                             // = H2, 0..23
        const int dy47 = t - h + 23;                        // 0..46
        const short* apb = kt + ((long)(dy47*49 + (24 - w0 + d)))*256 + n*16 + ih;
        const short* bpb = vp + ((long)((t + 8)*40 + (8 + d)))*256 + n*16 + ih;

        // prefetch all B for this t (12 independent 16B loads)
        bf16x8 bv[12];
        #pragma unroll
        for (int dxp = 0; dxp < 12; ++dxp)
            bv[dxp] = *(const bf16x8*)(bpb + dxp*512);      // x' += 2 per dxp

        bf16x8 av[4];
        av[0] = *(const bf16x8*)(apb);                      // ww=0
        av[1] = *(const bf16x8*)(apb - 256);                // ww=1
        av[2] = *(const bf16x8*)(apb - 512);                // ww=2
        av[3] = *(const bf16x8*)(apb - 768);                // ww=3

        #pragma unroll
        for (int dxp = 0; dxp < 12; ++dxp) {
            #pragma unroll
            for (int ww = 0; ww < 4; ++ww)
                acc[ww] = __builtin_amdgcn_mfma_f32_16x16x32_bf16(av[ww], bv[dxp], acc[ww], 0, 0, 0);
            if (dxp < 11) {
                av[2] = av[0];                              // A(2,dxp+1) = A(0,dxp)
                av[3] = av[1];                              // A(3,dxp+1) = A(1,dxp)
                av[0] = *(const bf16x8*)(apb + (2*dxp + 2)*256);
                av[1] = *(const bf16x8*)(apb + (2*dxp + 1)*256);
            }
        }
    }

    // ---- 8-wave reduce ----
    #pragma unroll
    for (int ww = 0; ww < 4; ++ww) red[wv][ww][lane] = acc[ww];
    __syncthreads();

    f32x4 s;
    if (wv < 4) {
        s = red[0][wv][lane];
        #pragma unroll
        for (int src = 1; src < 8; ++src) s += red[src][wv][lane];
    }
    __syncthreads();                  // all red reads done before lds2 overwrite

    float* lds2 = (float*)red;        // [4 ww][256 c2], 4 KB
    if (wv < 4) {
        const int c2b = n*16 + g*4;   // c2 = b*16 + o, o = g*4+e
        #pragma unroll
        for (int e = 0; e < 4; ++e) lds2[wv*256 + c2b + e] = s[e];
    }
    __syncthreads();

    if (tid < 256) {
        const float sc = 1.0f/576.0f;
        const float bb = bias[tid & 15];
        float4 o;
        o.x = lds2[0*256 + tid]*sc + bb;
        o.y = lds2[1*256 + tid]*sc + bb;
        o.z = lds2[2*256 + tid]*sc + bb;
        o.w = lds2[3*256 + tid]*sc + bb;
        *(float4*)(out + (size_t)tid*NPOS + h*24 + w0) = o;
    }
}

extern "C" void kernel_launch(void* const* d_in, const int* in_sizes, int n_in,
                              void* d_out, int out_size, void* d_ws, size_t ws_size,
                              hipStream_t stream)
{
    const float* v    = (const float*)d_in[0];
    const float* w1   = (const float*)d_in[1];
    const float* b1   = (const float*)d_in[2];
    const float* w2   = (const float*)d_in[3];
    const float* b2   = (const float*)d_in[4];
    const float* bias = (const float*)d_in[5];
    float* out = (float*)d_out;

    char* ws = (char*)d_ws;
    __hip_bfloat16* kt   = (__hip_bfloat16*)ws;                          // 1,179,136 B
    __hip_bfloat16* vpad = (__hip_bfloat16*)(ws + (size_t)KT_ELEMS*2);   //   819,200 B

    prep<<<dim3(PREP_BUILD_BLOCKS + PREP_PAD_BLOCKS), dim3(256), 0, stream>>>(
        v, w1, b1, w2, b2, kt, vpad);
    conv_direct<<<dim3(6, 24), dim3(512), 0, stream>>>(kt, vpad, bias, out);
}